// Round 7
// baseline (523.824 us; speedup 1.0000x reference)
//
#include <hip/hip_runtime.h>
#include <hip/hip_bf16.h>

constexpr int kB   = 4;
constexpr int kT   = 2048;
constexpr int kCIN = 2048;
constexpr int kHID = 1024;
constexpr int kEMB = 256;

typedef __bf16 bf16_t;
typedef __bf16 bf16x8 __attribute__((ext_vector_type(8)));
typedef __bf16 bf16x4 __attribute__((ext_vector_type(4)));
typedef float  f32x4  __attribute__((ext_vector_type(4)));

// async global->LDS 16B/lane (LDS dest = wave-uniform base + lane*16)
__device__ __forceinline__ void gll16(const void* g, void* l) {
  auto lp = reinterpret_cast<__attribute__((address_space(3))) uint32_t*>(
      reinterpret_cast<uintptr_t>(l));
  __builtin_amdgcn_global_load_lds(static_cast<const uint32_t*>(g), lp, 16, 0, 0);
}

// ================= GEMM core: C[m,n] += / = sum_k A[m,k]*B[n,k] ===================
// 128x128 tile, BK=64, 256 thr (2x2 waves of 64x64), mfma_f32_16x16x32_bf16.
// MODE 0: bf16 store, 2: f32 atomicAdd. A,B pre-offset (batch, k-slice). Klen % 64 == 0.
template <int MODE>
__device__ __forceinline__ void gemm_core(bf16_t* sA, bf16_t* sB,
                                          const bf16_t* A, const bf16_t* B, void* Cv,
                                          int lda, int ldb, int ldc,
                                          int m0, int n0, int Klen,
                                          const float* biasN) {
  const int tid = threadIdx.x;
  const int lane = tid & 63, wave = tid >> 6;
  const int wm = wave & 1, wn = wave >> 1;
  const int lm = lane & 15, q = lane >> 4;

  f32x4 acc[4][4];
#pragma unroll
  for (int i = 0; i < 4; i++)
#pragma unroll
    for (int j = 0; j < 4; j++)
#pragma unroll
      for (int r = 0; r < 4; r++) acc[i][j][r] = 0.f;

  const int srow = wave * 16 + (lane >> 2);
  const int scol = (lane & 3) * 8;
  const bf16_t* gA0 = A + (size_t)(m0 + srow) * lda + scol;
  const bf16_t* gA1 = gA0 + (size_t)64 * lda;
  const bf16_t* gB0 = B + (size_t)(n0 + srow) * ldb + scol;
  const bf16_t* gB1 = gB0 + (size_t)64 * ldb;
  bf16_t* lA0 = &sA[wave * 512];
  bf16_t* lA1 = &sA[64 * 32 + wave * 512];
  bf16_t* lB0 = &sB[wave * 512];
  bf16_t* lB1 = &sB[64 * 32 + wave * 512];

  for (int k0 = 0; k0 < Klen; k0 += 64) {
    __syncthreads();
    gll16(gA0 + k0,      lA0);
    gll16(gA0 + k0 + 32, lA0 + 4096);
    gll16(gA1 + k0,      lA1);
    gll16(gA1 + k0 + 32, lA1 + 4096);
    gll16(gB0 + k0,      lB0);
    gll16(gB0 + k0 + 32, lB0 + 4096);
    gll16(gB1 + k0,      lB1);
    gll16(gB1 + k0 + 32, lB1 + 4096);
    __syncthreads();

#pragma unroll
    for (int kk = 0; kk < 2; kk++) {
      bf16x8 af[4], bfr[4];
#pragma unroll
      for (int i = 0; i < 4; i++)
        af[i] = *(const bf16x8*)(&sA[kk * 4096 + (wm * 64 + i * 16 + lm) * 32 + q * 8]);
#pragma unroll
      for (int j = 0; j < 4; j++)
        bfr[j] = *(const bf16x8*)(&sB[kk * 4096 + (wn * 64 + j * 16 + lm) * 32 + q * 8]);
#pragma unroll
      for (int i = 0; i < 4; i++)
#pragma unroll
        for (int j = 0; j < 4; j++)
          acc[i][j] = __builtin_amdgcn_mfma_f32_16x16x32_bf16(af[i], bfr[j], acc[i][j], 0, 0, 0);
    }
  }

  // epilogue: C/D layout col=lane&15, row=(lane>>4)*4+reg
#pragma unroll
  for (int i = 0; i < 4; i++) {
    const int gmb = m0 + wm * 64 + i * 16 + q * 4;
#pragma unroll
    for (int j = 0; j < 4; j++) {
      const int gn = n0 + wn * 64 + j * 16 + lm;
      float bn_ = biasN ? biasN[gn] : 0.f;
#pragma unroll
      for (int r = 0; r < 4; r++) {
        const int gm = gmb + r;
        float v = acc[i][j][r] + bn_;
        const size_t idx = (size_t)gm * ldc + gn;
        if (MODE == 0) ((bf16_t*)Cv)[idx] = (bf16_t)v;
        else           atomicAdd(&((float*)Cv)[idx], v);
      }
    }
  }
}

// ================= dispatch 1: all prep (casts + w_w transpose + biases) ===========
__global__ __launch_bounds__(256) void k_prep(const float* __restrict__ x,
                                              const float* __restrict__ th,
                                              const float* __restrict__ ph,
                                              const float* __restrict__ g,
                                              const float* __restrict__ emb,
                                              const float* __restrict__ w_w,
                                              const float* __restrict__ w_b,
                                              const float* __restrict__ emb_b,
                                              const float* __restrict__ tb,
                                              const float* __restrict__ pb,
                                              const float* __restrict__ gb,
                                              bf16_t* __restrict__ xbf,
                                              bf16_t* __restrict__ wqkv,
                                              bf16_t* __restrict__ embbf,
                                              bf16_t* __restrict__ wwT,
                                              float* __restrict__ biase,
                                              float* __restrict__ bqkv) {
  __shared__ float tile[64 * 66];
  const int b = blockIdx.x;
  if (b < 23040) {  // casts
    const float* in; bf16_t* out; long i;
    if (b < 16384)      { in = x;   out = xbf;                          i = (long)b * 256 + threadIdx.x; }
    else if (b < 18432) { in = th;  out = wqkv;                         i = (long)(b - 16384) * 256 + threadIdx.x; }
    else if (b < 20480) { in = ph;  out = wqkv + (size_t)kHID * kCIN;   i = (long)(b - 18432) * 256 + threadIdx.x; }
    else if (b < 22528) { in = g;   out = wqkv + (size_t)2 * kHID * kCIN; i = (long)(b - 20480) * 256 + threadIdx.x; }
    else                { in = emb; out = embbf;                        i = (long)(b - 22528) * 256 + threadIdx.x; }
    float4 v = ((const float4*)in)[i];
    bf16x4 o;
    o[0] = (bf16_t)v.x; o[1] = (bf16_t)v.y; o[2] = (bf16_t)v.z; o[3] = (bf16_t)v.w;
    ((bf16x4*)out)[i] = o;
  } else if (b < 23552) {  // w_w (CIN,HID) -> wwT (HID,CIN)
    int j = b - 23040;
    int h0 = (j & 15) * 64, c0 = (j >> 4) * 64;
#pragma unroll
    for (int k = 0; k < 16; k++) {
      int e = k * 256 + threadIdx.x;
      int r = e >> 6, c = e & 63;
      tile[r * 66 + c] = w_w[(size_t)(c0 + r) * kHID + h0 + c];
    }
    __syncthreads();
#pragma unroll
    for (int k = 0; k < 16; k++) {
      int e = k * 256 + threadIdx.x;
      int r = e >> 6, c = e & 63;
      wwT[(size_t)(h0 + r) * kCIN + c0 + c] = (bf16_t)tile[c * 66 + r];
    }
  } else if (b < 23808) {  // bias_e
    int e = b - 23552;
    float acc = 0.f;
    for (int c = threadIdx.x; c < kCIN; c += 256)
      acc += emb[(size_t)e * kCIN + c] * w_b[c];
#pragma unroll
    for (int o = 32; o > 0; o >>= 1) acc += __shfl_xor(acc, o, 64);
    __syncthreads();
    if ((threadIdx.x & 63) == 0) tile[threadIdx.x >> 6] = acc;
    __syncthreads();
    if (threadIdx.x == 0) biase[e] = tile[0] + tile[1] + tile[2] + tile[3] + emb_b[e];
  } else {  // concat biases -> bqkv[3072]
    int i = (b - 23808) * 256 + threadIdx.x;
    if (i < 3072)
      bqkv[i] = i < 1024 ? tb[i] : (i < 2048 ? pb[i - 1024] : gb[i - 2048]);
  }
}

// ========= dispatch 2a: QKV GEMM alone (homogeneous; round-5 proven 122 µs) ========
__global__ __launch_bounds__(256) void k_qkv(const bf16_t* __restrict__ xbf,
                                             const bf16_t* __restrict__ wqkv,
                                             bf16_t* __restrict__ xtphi,
                                             const float* __restrict__ bqkv) {
  __shared__ bf16_t sA[8192], sB[8192];
  gemm_core<0>(sA, sB, xbf, wqkv, xtphi, 2048, 2048, 3072,
               blockIdx.x * 128, blockIdx.y * 128, 2048, bqkv);
}

// ========= dispatch 2b: S1-triangular (544) + M (16) = 560 blocks ==================
__global__ __launch_bounds__(256) void k_s1m(const bf16_t* __restrict__ xbf,
                                             const bf16_t* __restrict__ embbf,
                                             const bf16_t* __restrict__ wwT,
                                             bf16_t* __restrict__ S1,
                                             bf16_t* __restrict__ Mbf) {
  __shared__ bf16_t sA[8192], sB[8192];
  const int bid = blockIdx.x;
  if (bid < 544) {  // S1[z] = x[z] @ x[z]^T, upper triangular tiles (nb=16)
    int z = bid / 136, t = bid % 136;
    int r = 0;
    while (t >= 16 - r) { t -= 16 - r; r++; }
    const bf16_t* Az = xbf + (size_t)z * kT * kCIN;
    gemm_core<0>(sA, sB, Az, Az, S1 + (size_t)z * kT * kT, 2048, 2048, 2048,
                 r * 128, (r + t) * 128, 2048, nullptr);
  } else {  // M = emb @ w_w  (256 x 1024, K=2048)
    int m = bid - 544;
    gemm_core<0>(sA, sB, embbf, wwT, Mbf, 2048, 2048, 1024,
                 (m & 1) * 128, (m >> 1) * 128, 2048, nullptr);
  }
}

// ====== dispatch 3: S2(1024) + mirror(1984) + xg-transpose(2048) + zero-out(2048) ==
__global__ __launch_bounds__(256) void k_mid(const bf16_t* __restrict__ xtphi,
                                             bf16_t* __restrict__ S2,
                                             bf16_t* __restrict__ S1,
                                             bf16_t* __restrict__ xgT,
                                             float* __restrict__ out) {
  __shared__ bf16_t sA[8192], sB[8192];
  const int bid = blockIdx.x;
  const size_t T2 = (size_t)kT * kT;
  if (bid < 1024) {  // S2[z] = xphi[z] @ xt[z]^T (K=1024, slices of xtphi ld 3072)
    int bm = bid & 15, bn = (bid >> 4) & 15, z = bid >> 8;
    const bf16_t* base = xtphi + (size_t)z * kT * 3072;
    gemm_core<0>(sA, sB, base + 1024, base, S2 + (size_t)z * T2, 3072, 3072, 2048,
                 bm * 128, bn * 128, 1024, nullptr);
  } else if (bid < 3008) {  // mirror S1 upper -> lower (64x64 tiles, p>q)
    int j = bid - 1024;
    int z = j / 496, t = j % 496, qq = 0;
    while (t >= 31 - qq) { t -= 31 - qq; qq++; }
    int p = qq + 1 + t;
    bf16_t* tile = sA;
    const size_t base = (size_t)z * T2;
#pragma unroll
    for (int k = 0; k < 16; k++) {
      int e = k * 256 + threadIdx.x;
      int r = e >> 6, c = e & 63;
      tile[r * 66 + c] = S1[base + (size_t)(qq * 64 + r) * kT + p * 64 + c];
    }
    __syncthreads();
#pragma unroll
    for (int k = 0; k < 16; k++) {
      int e = k * 256 + threadIdx.x;
      int r = e >> 6, c = e & 63;
      S1[base + (size_t)(p * 64 + r) * kT + qq * 64 + c] = tile[c * 66 + r];
    }
  } else if (bid < 5056) {  // xgT[z](h,t) from xg slice of xtphi
    int j = bid - 3008;
    int hb = j & 15, tb = (j >> 4) & 31, z = j >> 9;
    bf16_t* tile = sA;
#pragma unroll
    for (int k = 0; k < 16; k++) {
      int e = k * 256 + threadIdx.x;
      int r = e >> 6, c = e & 63;  // r: t, c: h
      tile[r * 66 + c] = xtphi[(size_t)(z * kT + tb * 64 + r) * 3072 + 2048 + hb * 64 + c];
    }
    __syncthreads();
#pragma unroll
    for (int k = 0; k < 16; k++) {
      int e = k * 256 + threadIdx.x;
      int r = e >> 6, c = e & 63;  // r: h, c: t
      xgT[(size_t)z * kHID * kT + (size_t)(hb * 64 + r) * kT + tb * 64 + c] = tile[c * 66 + r];
    }
  } else {  // zero d_out (2M f32 = 524288 float4)
    long i = (long)(bid - 5056) * 256 + threadIdx.x;
    ((float4*)out)[i] = make_float4(0.f, 0.f, 0.f, 0.f);
  }
}

// ================= dispatch 4: moca (both passes) ==================================
__global__ __launch_bounds__(256) void k_moca(const bf16_t* __restrict__ S1,
                                              const bf16_t* __restrict__ S2,
                                              bf16_t* __restrict__ dst,
                                              const float* __restrict__ rou_w,
                                              const float* __restrict__ rou_b) {
  __shared__ float s[4];
  const int t = blockIdx.x, b = blockIdx.y;
  const size_t T2 = (size_t)kT * kT;
  const bf16_t* src = (b < 2) ? S1 : S2;
  const int pb = (b < 2) ? 2 * b : 2 * (b - 2);
  const bf16_t* rA = src + (size_t)pb * T2 + (size_t)t * kT;
  const bf16_t* rB = rA + T2;
  const int base = threadIdx.x * 8;

  float va[8], vb[8];
  {
    bf16x8 a = *(const bf16x8*)(rA + base);
    bf16x8 bb = *(const bf16x8*)(rB + base);
#pragma unroll
    for (int j = 0; j < 8; j++) { va[j] = (float)a[j]; vb[j] = (float)bb[j]; }
  }
  auto red_max = [&](float v) {
#pragma unroll
    for (int o = 32; o > 0; o >>= 1) v = fmaxf(v, __shfl_xor(v, o, 64));
    __syncthreads();
    if ((threadIdx.x & 63) == 0) s[threadIdx.x >> 6] = v;
    __syncthreads();
    return fmaxf(fmaxf(s[0], s[1]), fmaxf(s[2], s[3]));
  };
  auto red_sum = [&](float v) {
#pragma unroll
    for (int o = 32; o > 0; o >>= 1) v += __shfl_xor(v, o, 64);
    __syncthreads();
    if ((threadIdx.x & 63) == 0) s[threadIdx.x >> 6] = v;
    __syncthreads();
    return (s[0] + s[1]) + (s[2] + s[3]);
  };

  float m = -1e30f, acc;
#pragma unroll
  for (int j = 0; j < 8; j++) m = fmaxf(m, va[j]);
  m = red_max(m); acc = 0.f;
#pragma unroll
  for (int j = 0; j < 8; j++) { va[j] = __expf(va[j] - m); acc += va[j]; }
  float invA = 1.f / red_sum(acc);

  m = -1e30f;
#pragma unroll
  for (int j = 0; j < 8; j++) m = fmaxf(m, vb[j]);
  m = red_max(m); acc = 0.f;
#pragma unroll
  for (int j = 0; j < 8; j++) { vb[j] = __expf(vb[j] - m); acc += vb[j]; }
  float invB = 1.f / red_sum(acc);

  const float r0 = rou_w[0], r1 = rou_w[1], rb = rou_b[0];
#pragma unroll
  for (int j = 0; j < 8; j++) va[j] = r0 * va[j] * invA + r1 * vb[j] * invB + rb;

  m = -1e30f;
#pragma unroll
  for (int j = 0; j < 8; j++) m = fmaxf(m, va[j]);
  m = red_max(m); acc = 0.f;
#pragma unroll
  for (int j = 0; j < 8; j++) { va[j] = __expf(va[j] - m); acc += va[j]; }
  float invC = 1.f / red_sum(acc);

  bf16x8 o;
#pragma unroll
  for (int j = 0; j < 8; j++) o[j] = (bf16_t)(va[j] * invC);
  *(bf16x8*)(dst + (size_t)b * T2 + (size_t)t * kT + base) = o;
}

// ================= dispatch 5: mocab -> mocaT (batched TxT transpose) ==============
__global__ __launch_bounds__(256) void k_mocaT(const bf16_t* __restrict__ in,
                                               bf16_t* __restrict__ out) {
  __shared__ bf16_t tile[64 * 66];
  size_t base = (size_t)blockIdx.z * kT * kT;
  int r0 = blockIdx.y * 64, c0 = blockIdx.x * 64;
#pragma unroll
  for (int k = 0; k < 16; k++) {
    int e = k * 256 + threadIdx.x;
    int r = e >> 6, c = e & 63;
    tile[r * 66 + c] = in[base + (size_t)(r0 + r) * kT + c0 + c];
  }
  __syncthreads();
#pragma unroll
  for (int k = 0; k < 16; k++) {
    int e = k * 256 + threadIdx.x;
    int r = e >> 6, c = e & 63;
    out[base + (size_t)(c0 + r) * kT + r0 + c] = tile[c * 66 + r];
  }
}

// ====== dispatch 6: yT GEMM(512) + x@emb^T split-K4 atomic into out (512) ==========
__global__ __launch_bounds__(256) void k_tail1(const bf16_t* __restrict__ mocaT,
                                               const bf16_t* __restrict__ xgT,
                                               bf16_t* __restrict__ yT,
                                               const bf16_t* __restrict__ xbf,
                                               const bf16_t* __restrict__ embbf,
                                               float* __restrict__ out,
                                               const float* __restrict__ biase) {
  __shared__ bf16_t sA[8192], sB[8192];
  const int bid = blockIdx.x;
  if (bid < 512) {  // yT[z] = mocaT[z] @ xgT[z]^T  (2048 x 1024, K=2048)
    int bm = bid & 15, bn = (bid >> 4) & 7, z = bid >> 7;
    gemm_core<0>(sA, sB, mocaT + (size_t)z * kT * kT, xgT + (size_t)z * kHID * kT,
                 yT + (size_t)z * kT * kHID, 2048, 2048, 1024,
                 bm * 128, bn * 128, 2048, nullptr);
  } else {  // out += x @ emb^T slice (K=512 each), + biase on slice 0
    int r = bid - 512;
    int bm = r & 63, bn = (r >> 6) & 1, ks = r >> 7;
    gemm_core<2>(sA, sB, xbf + ks * 512, embbf + ks * 512, out, 2048, 2048, 256,
                 bm * 128, bn * 128, 512, ks == 0 ? biase : nullptr);
  }
}

// ================= dispatch 7: out += yT @ M^T split-K4 atomic (512) ===============
__global__ __launch_bounds__(256) void k_tail2(const bf16_t* __restrict__ yT,
                                               const bf16_t* __restrict__ Mbf,
                                               float* __restrict__ out) {
  __shared__ bf16_t sA[8192], sB[8192];
  const int bid = blockIdx.x;
  int bm = bid & 63, bn = (bid >> 6) & 1, ks = bid >> 7;
  gemm_core<2>(sA, sB, yT + ks * 256, Mbf + ks * 256, out, 1024, 1024, 256,
               bm * 128, bn * 128, 256, nullptr);
}

extern "C" void kernel_launch(void* const* d_in, const int* in_sizes, int n_in,
                              void* d_out, int out_size, void* d_ws, size_t ws_size,
                              hipStream_t stream) {
  const float* x       = (const float*)d_in[0];
  const float* theta_w = (const float*)d_in[1];
  const float* theta_b = (const float*)d_in[2];
  const float* phi_w   = (const float*)d_in[3];
  const float* phi_b   = (const float*)d_in[4];
  const float* g_w     = (const float*)d_in[5];
  const float* g_b     = (const float*)d_in[6];
  const float* rou_w   = (const float*)d_in[7];
  const float* rou_b   = (const float*)d_in[8];
  const float* w_w     = (const float*)d_in[9];
  const float* w_b     = (const float*)d_in[10];
  const float* emb_w   = (const float*)d_in[11];
  const float* emb_b   = (const float*)d_in[12];
  float* out = (float*)d_out;

  char* ws = (char*)d_ws;
  size_t off = 0;
  auto alloc = [&](size_t bytes) -> char* {
    off = (off + 255) & ~(size_t)255;
    char* p = ws + off;
    off += bytes;
    return p;
  };

  const size_t BT = (size_t)kB * kT;   // 8192
  const size_t T2 = (size_t)kT * kT;   // 4M

  // ~220 MB total (< 256 MB; round-1 lesson)
  bf16_t* xbf   = (bf16_t*)alloc(BT * kCIN * 2);               // 33.5 MB
  bf16_t* wqkv  = (bf16_t*)alloc((size_t)3 * kHID * kCIN * 2); // 12.6 MB
  bf16_t* embbf = (bf16_t*)alloc((size_t)kEMB * kCIN * 2);     // 1.0 MB
  bf16_t* wwT   = (bf16_t*)alloc((size_t)kHID * kCIN * 2);     // 4.2 MB
  bf16_t* xtphi = (bf16_t*)alloc(BT * 3072 * 2);               // 50.3 MB [xt|xphi|xg]
  bf16_t* xgT   = (bf16_t*)alloc((size_t)kB * kHID * kT * 2);  // 16.8 MB
  bf16_t* mocab = (bf16_t*)alloc((size_t)kB * T2 * 2);         // 33.5 MB
  bf16_t* Mbf   = (bf16_t*)alloc((size_t)kEMB * kHID * 2);     // 0.5 MB
  float*  biase = (float*)alloc((size_t)kEMB * 4);
  float*  bqkv  = (float*)alloc((size_t)3072 * 4);
  bf16_t* S1    = (bf16_t*)alloc((size_t)kB * T2 * 2);         // 33.5 MB
  bf16_t* S2    = (bf16_t*)alloc((size_t)kB * T2 * 2);         // 33.5 MB
  // aliases over dead regions:
  bf16_t* mocaT = (bf16_t*)xtphi;  // xtphi dead after k_mid (S2 GEMM + xg transpose)
  bf16_t* yT    = (bf16_t*)S2;     // S2 dead after k_moca (needs 16.8 <= 33.5)

  // 1: prep (casts + wwT + bias_e + bqkv)
  k_prep<<<dim3(23820), 256, 0, stream>>>(x, theta_w, phi_w, g_w, emb_w, w_w, w_b,
                                          emb_b, theta_b, phi_b, g_b,
                                          xbf, wqkv, embbf, wwT, biase, bqkv);
  // 2a: QKV alone (homogeneous — k_mega1 merge regressed it, round-6 lesson)
  k_qkv<<<dim3(64, 24), 256, 0, stream>>>(xbf, wqkv, xtphi, bqkv);
  // 2b: S1-triangular + M
  k_s1m<<<dim3(560), 256, 0, stream>>>(xbf, embbf, wwT, S1, Mbf);
  // 3: S2 + mirror(S1) + xgT + zero(out)
  k_mid<<<dim3(7104), 256, 0, stream>>>(xtphi, S2, S1, xgT, out);
  // 4: moca (both passes)
  k_moca<<<dim3(kT, kB), 256, 0, stream>>>(S1, S2, mocab, rou_w, rou_b);
  // 5: mocaT (overwrites dead xtphi)
  k_mocaT<<<dim3(32, 32, kB), 256, 0, stream>>>(mocab, mocaT);
  // 6: yT GEMM (over dead S2) + x@emb^T split-K atomic + biase
  k_tail1<<<dim3(1024), 256, 0, stream>>>(mocaT, xgT, yT, xbf, embbf, out, biase);
  // 7: out += yT @ M^T split-K atomic
  k_tail2<<<dim3(512), 256, 0, stream>>>(yT, Mbf, out);
}